// Round 1
// baseline (150.872 us; speedup 1.0000x reference)
//
#include <hip/hip_runtime.h>
#include <stdint.h>

#define B 512
#define D 128
#define HALF (B * B / 2) /* 131072 */

__device__ __forceinline__ uint32_t rotl32(uint32_t x, uint32_t r) {
  return (x << r) | (x >> (32u - r));
}

// Exact JAX/XLA threefry2x32 (20 rounds, key-schedule injections every 4).
__device__ __forceinline__ void threefry2x32(uint32_t k0, uint32_t k1,
                                             uint32_t x0, uint32_t x1,
                                             uint32_t& y0, uint32_t& y1) {
  uint32_t k2 = k0 ^ k1 ^ 0x1BD11BDAu;
  x0 += k0; x1 += k1;
#define TF_R(r) { x0 += x1; x1 = rotl32(x1, r); x1 ^= x0; }
  TF_R(13) TF_R(15) TF_R(26) TF_R(6)
  x0 += k1; x1 += k2 + 1u;
  TF_R(17) TF_R(29) TF_R(16) TF_R(24)
  x0 += k2; x1 += k0 + 2u;
  TF_R(13) TF_R(15) TF_R(26) TF_R(6)
  x0 += k0; x1 += k1 + 3u;
  TF_R(17) TF_R(29) TF_R(16) TF_R(24)
  x0 += k1; x1 += k2 + 4u;
  TF_R(13) TF_R(15) TF_R(26) TF_R(6)
  x0 += k2; x1 += k0 + 5u;
#undef TF_R
  y0 = x0; y1 = x1;
}

// K0: squared norms, one wave per row.
__global__ __launch_bounds__(64) void sq_kernel(const float* __restrict__ emb,
                                                float* __restrict__ sq) {
  int i = blockIdx.x;
  int lane = threadIdx.x; // 0..63, 64 lanes x float2 = 128 floats
  const float2* e2 = reinterpret_cast<const float2*>(emb + (size_t)i * D);
  float2 a = e2[lane];
  float s = a.x * a.x + a.y * a.y;
  #pragma unroll
  for (int off = 32; off; off >>= 1) s += __shfl_xor(s, off);
  if (lane == 0) sq[i] = s;
}

// K1: dist row i + hard-negative argmin (first-occurrence ties) + has_neg.
__global__ __launch_bounds__(256) void dist_kernel(
    const float* __restrict__ emb, const float* __restrict__ sq,
    const int* __restrict__ labels, float* __restrict__ dist,
    int* __restrict__ hard_idx, int* __restrict__ has_neg) {
  __shared__ float ei[D];
  __shared__ float rmin[256];
  __shared__ int ridx[256];
  int i = blockIdx.x;
  int t = threadIdx.x;
  if (t < D) ei[t] = emb[(size_t)i * D + t];
  __syncthreads();
  int lab_i = labels[i];
  float sqi = sq[i];
  float bestv = 3.4e38f;
  int bestj = -1;
  const float4* e4i = reinterpret_cast<const float4*>(ei);
  for (int jj = 0; jj < 2; ++jj) {
    int j = t + jj * 256;
    const float4* ej = reinterpret_cast<const float4*>(emb + (size_t)j * D);
    float dot = 0.f;
    #pragma unroll
    for (int d4 = 0; d4 < D / 4; ++d4) {
      float4 v = ej[d4];
      float4 w = e4i[d4];
      dot += v.x * w.x + v.y * w.y + v.z * w.z + v.w * w.w;
    }
    float d2 = sqi + sq[j] - 2.f * dot;
    float dd = sqrtf(fmaxf(d2, 0.f));
    dist[(size_t)i * B + j] = dd;
    if (labels[j] != lab_i) {
      if (bestj < 0 || dd < bestv) { bestv = dd; bestj = j; } // j ascending -> first min kept
    }
  }
  rmin[t] = bestv; ridx[t] = bestj;
  __syncthreads();
  for (int s = 128; s; s >>= 1) {
    if (t < s) {
      float ov = rmin[t + s]; int oj = ridx[t + s];
      if (oj >= 0 && (ridx[t] < 0 || ov < rmin[t] ||
                      (ov == rmin[t] && oj < ridx[t]))) {
        rmin[t] = ov; ridx[t] = oj;
      }
    }
    __syncthreads();
  }
  if (t == 0) {
    hard_idx[i] = (ridx[0] < 0) ? 0 : ridx[0];
    has_neg[i] = (ridx[0] >= 0) ? 1 : 0;
  }
}

// K2: one block per anchor p; 4 waves scan rows i; lanes scan j.
// Semi-hard selection = integer argmax of (threefry bits >> 9), ties -> lowest j.
__global__ __launch_bounds__(256) void triplet_kernel(
    const float* __restrict__ dist, const int* __restrict__ labels,
    const int* __restrict__ hard_idx, const int* __restrict__ has_neg,
    double* __restrict__ loss_sum, unsigned int* __restrict__ cnt) {
  __shared__ int slab[B];
  int p = blockIdx.x;
  int t = threadIdx.x;
  slab[t] = labels[t];
  slab[t + 256] = labels[t + 256];
  __syncthreads();
  int wave = t >> 6, lane = t & 63;

  // keys[p] from split(key(42), 512): out[i] = i<512 ? y0(i,i+512) : y1(i-512,i)
  uint32_t kp0, kp1;
  {
    uint32_t i0 = 2u * (uint32_t)p, i1 = i0 + 1u;
    uint32_t a0, a1, b0, b1;
    if (p < 256) {
      threefry2x32(0u, 42u, i0, i0 + 512u, a0, a1);
      threefry2x32(0u, 42u, i1, i1 + 512u, b0, b1);
      kp0 = a0; kp1 = b0;
    } else {
      threefry2x32(0u, 42u, i0 - 512u, i0, a0, a1);
      threefry2x32(0u, 42u, i1 - 512u, i1, b0, b1);
      kp0 = a1; kp1 = b1;
    }
  }
  int lab_p = slab[p];
  double wsum = 0.0;
  unsigned int wcnt = 0;

  for (int i = wave; i < B; i += 4) {
    if (i == p || slab[i] != lab_p || !has_neg[i]) continue; // ~1/8 of rows survive
    const float* drow = dist + (size_t)i * B;
    float pos_d = drow[p];
    float hiv = pos_d + 1.0f; // margin = 1.0
    uint32_t rowbase = (uint32_t)(((i < 256) ? i : (i - 256)) * B);
    bool take_hi = (i >= 256);
    uint32_t bestbits = 0u;
    int bestj = -1;
    #pragma unroll
    for (int jc = 0; jc < 8; ++jc) {
      int j = jc * 64 + lane;
      float dd = drow[j];
      bool m = (slab[j] != lab_p) && (dd > pos_d) && (dd < hiv);
      if (__any(m)) {
        uint32_t y0, y1;
        threefry2x32(kp0, kp1, rowbase + (uint32_t)j,
                     rowbase + (uint32_t)j + (uint32_t)HALF, y0, y1);
        uint32_t bits = (take_hi ? y1 : y0) >> 9;
        if (m && (bestj < 0 || bits > bestbits)) { bestbits = bits; bestj = j; }
      }
    }
    // wave-level lexicographic reduce: max bits, ties -> min j
    #pragma unroll
    for (int off = 32; off; off >>= 1) {
      uint32_t ob = (uint32_t)__shfl_xor((int)bestbits, off);
      int oj = __shfl_xor(bestj, off);
      if (oj >= 0 && (bestj < 0 || ob > bestbits ||
                      (ob == bestbits && oj < bestj))) {
        bestbits = ob; bestj = oj;
      }
    }
    int idx = (bestj >= 0) ? bestj : hard_idx[i];
    float neg_d = drow[idx];
    float tl = pos_d - neg_d + 1.0f;
    if (tl > 0.f) { wsum += (double)tl; wcnt++; }
  }
  if (lane == 0) {
    if (wsum != 0.0) atomicAdd(loss_sum, wsum);
    if (wcnt) atomicAdd(cnt, wcnt);
  }
}

__global__ void finalize_kernel(const double* __restrict__ loss_sum,
                                const unsigned int* __restrict__ cnt,
                                float* __restrict__ out) {
  if (threadIdx.x == 0 && blockIdx.x == 0) {
    unsigned int c = *cnt;
    out[0] = c ? (float)(*loss_sum / (double)c) : 0.0f;
  }
}

extern "C" void kernel_launch(void* const* d_in, const int* in_sizes, int n_in,
                              void* d_out, int out_size, void* d_ws, size_t ws_size,
                              hipStream_t stream) {
  const float* emb = (const float*)d_in[0];
  const int* labels = (const int*)d_in[1];
  float* out = (float*)d_out;
  char* ws = (char*)d_ws;

  float* dist = (float*)ws;                              // 512*512*4 = 1 MB
  float* sq = (float*)(ws + 1048576);                    // 2 KB
  int* hard_idx = (int*)(ws + 1048576 + 2048);           // 2 KB
  int* has_neg = (int*)(ws + 1048576 + 4096);            // 2 KB
  double* loss_sum = (double*)(ws + 1048576 + 6144);     // 8 B
  unsigned int* cnt = (unsigned int*)(ws + 1048576 + 6144 + 8);

  hipMemsetAsync(ws + 1048576 + 6144, 0, 16, stream);
  sq_kernel<<<B, 64, 0, stream>>>(emb, sq);
  dist_kernel<<<B, 256, 0, stream>>>(emb, sq, labels, dist, hard_idx, has_neg);
  triplet_kernel<<<B, 256, 0, stream>>>(dist, labels, hard_idx, has_neg, loss_sum, cnt);
  finalize_kernel<<<1, 64, 0, stream>>>(loss_sum, cnt, out);
}

// Round 2
// 88.205 us; speedup vs baseline: 1.7105x; 1.7105x over previous
//
#include <hip/hip_runtime.h>
#include <stdint.h>

#define B 512
#define D 128
#define NLAB 8
#define HALFC 131072u
#define SPLIT 8
#define NSLOT (SPLIT * 4)
#define NPART (B * SPLIT)

__device__ __forceinline__ uint32_t rotl32(uint32_t x, uint32_t r) {
  return (x << r) | (x >> (32u - r));
}

// Exact JAX/XLA threefry2x32 (20 rounds, key-schedule injections every 4).
__device__ __forceinline__ void threefry2x32(uint32_t k0, uint32_t k1,
                                             uint32_t x0, uint32_t x1,
                                             uint32_t& y0, uint32_t& y1) {
  uint32_t k2 = k0 ^ k1 ^ 0x1BD11BDAu;
  x0 += k0; x1 += k1;
#define TF_R(r) { x0 += x1; x1 = rotl32(x1, r); x1 ^= x0; }
  TF_R(13) TF_R(15) TF_R(26) TF_R(6)
  x0 += k1; x1 += k2 + 1u;
  TF_R(17) TF_R(29) TF_R(16) TF_R(24)
  x0 += k2; x1 += k0 + 2u;
  TF_R(13) TF_R(15) TF_R(26) TF_R(6)
  x0 += k0; x1 += k1 + 3u;
  TF_R(17) TF_R(29) TF_R(16) TF_R(24)
  x0 += k1; x1 += k2 + 4u;
  TF_R(13) TF_R(15) TF_R(26) TF_R(6)
  x0 += k2; x1 += k0 + 5u;
#undef TF_R
  y0 = x0; y1 = x1;
}

// K0: squared norms, one wave per row.
__global__ __launch_bounds__(64) void sq_kernel(const float* __restrict__ emb,
                                                float* __restrict__ sq) {
  int i = blockIdx.x;
  int lane = threadIdx.x;
  const float2* e2 = reinterpret_cast<const float2*>(emb + (size_t)i * D);
  float2 a = e2[lane];
  float s = a.x * a.x + a.y * a.y;
  #pragma unroll
  for (int off = 32; off; off >>= 1) s += __shfl_xor(s, off);
  if (lane == 0) sq[i] = s;
}

// K_list: 1 block, 512 threads (8 waves). Wave w builds the deterministic
// (ascending-i) list of rows with label w AND has_neg (= hist[w] != B).
__global__ __launch_bounds__(512) void list_kernel(const int* __restrict__ labels,
                                                   int* __restrict__ lists,
                                                   int* __restrict__ lcount) {
  __shared__ int slab[B];
  __shared__ int hist[NLAB];
  int t = threadIdx.x;
  slab[t] = labels[t];
  if (t < NLAB) hist[t] = 0;
  __syncthreads();
  atomicAdd(&hist[slab[t]], 1);
  __syncthreads();
  int w = t >> 6, lane = t & 63;
  bool group_ok = (hist[w] != B);  // has_neg for every row of label w
  int base = 0;
  for (int c = 0; c < 8; ++c) {
    int i = c * 64 + lane;
    bool valid = group_ok && (slab[i] == w);
    unsigned long long m = __ballot(valid);
    if (valid) {
      int off = __popcll(m & ((1ull << lane) - 1ull));
      lists[w * B + base + off] = i;
    }
    base += __popcll(m);
  }
  if (lane == 0) lcount[w] = base;
}

// K1: dist row i + hard-negative argmin (first-occurrence ties).
__global__ __launch_bounds__(256) void dist_kernel(
    const float* __restrict__ emb, const float* __restrict__ sq,
    const int* __restrict__ labels, float* __restrict__ dist,
    int* __restrict__ hard_idx) {
  __shared__ float ei[D];
  __shared__ float rmin[256];
  __shared__ int ridx[256];
  int i = blockIdx.x;
  int t = threadIdx.x;
  if (t < D) ei[t] = emb[(size_t)i * D + t];
  __syncthreads();
  int lab_i = labels[i];
  float sqi = sq[i];
  float bestv = 3.4e38f;
  int bestj = -1;
  const float4* e4i = reinterpret_cast<const float4*>(ei);
  for (int jj = 0; jj < 2; ++jj) {
    int j = t + jj * 256;
    const float4* ej = reinterpret_cast<const float4*>(emb + (size_t)j * D);
    float dot = 0.f;
    #pragma unroll
    for (int d4 = 0; d4 < D / 4; ++d4) {
      float4 v = ej[d4];
      float4 w = e4i[d4];
      dot += v.x * w.x + v.y * w.y + v.z * w.z + v.w * w.w;
    }
    float d2 = sqi + sq[j] - 2.f * dot;
    float dd = sqrtf(fmaxf(d2, 0.f));
    dist[(size_t)i * B + j] = dd;
    if (labels[j] != lab_i) {
      if (bestj < 0 || dd < bestv) { bestv = dd; bestj = j; }
    }
  }
  rmin[t] = bestv; ridx[t] = bestj;
  __syncthreads();
  for (int s = 128; s; s >>= 1) {
    if (t < s) {
      float ov = rmin[t + s]; int oj = ridx[t + s];
      if (oj >= 0 && (ridx[t] < 0 || ov < rmin[t] ||
                      (ov == rmin[t] && oj < ridx[t]))) {
        rmin[t] = ov; ridx[t] = oj;
      }
    }
    __syncthreads();
  }
  if (t == 0) hard_idx[i] = (ridx[0] < 0) ? 0 : ridx[0];
}

// K2: SPLIT blocks per anchor p; 32 wave-slots scan the per-label row list.
__global__ __launch_bounds__(256) void triplet_kernel(
    const float* __restrict__ dist, const int* __restrict__ labels,
    const int* __restrict__ hard_idx, const int* __restrict__ lists,
    const int* __restrict__ lcount, double* __restrict__ partials,
    int* __restrict__ pcnt) {
  __shared__ int slab[B];
  __shared__ double lsum[4];
  __shared__ unsigned int lcnt[4];
  int bid = blockIdx.x;
  int p = bid >> 3;       // SPLIT = 8
  int sub = bid & 7;
  int t = threadIdx.x;
  slab[t] = labels[t];
  slab[t + 256] = labels[t + 256];
  __syncthreads();
  int wave = t >> 6, lane = t & 63;
  int slot = sub * 4 + wave;  // 0..31

  // keys[p] from split(key(42), 512): out[i] = i<512 ? y0(i,i+512) : y1(i-512,i)
  uint32_t kp0, kp1;
  {
    uint32_t i0 = 2u * (uint32_t)p, i1 = i0 + 1u;
    uint32_t a0, a1, b0, b1;
    if (p < 256) {
      threefry2x32(0u, 42u, i0, i0 + 512u, a0, a1);
      threefry2x32(0u, 42u, i1, i1 + 512u, b0, b1);
      kp0 = a0; kp1 = b0;
    } else {
      threefry2x32(0u, 42u, i0 - 512u, i0, a0, a1);
      threefry2x32(0u, 42u, i1 - 512u, i1, b0, b1);
      kp0 = a1; kp1 = b1;
    }
  }
  int lab_p = slab[p];
  int n = lcount[lab_p];
  const int* __restrict__ mylist = lists + lab_p * B;
  double wsum = 0.0;
  unsigned int wcnt = 0;

  for (int k = slot; k < n; k += NSLOT) {
    int i = mylist[k];
    if (i == p) continue;
    const float* __restrict__ drow = dist + (size_t)i * B;
    float pos_d = drow[p];
    float hiv = pos_d + 1.0f;  // margin = 1.0
    uint32_t rowbase = (uint32_t)(((i < 256) ? i : (i - 256)) * B);
    bool take_hi = (i >= 256);
    uint32_t bestbits = 0u;
    int bestj = -1;
    #pragma unroll
    for (int jc = 0; jc < 8; ++jc) {
      int j = jc * 64 + lane;
      float dd = drow[j];
      bool m = (slab[j] != lab_p) && (dd > pos_d) && (dd < hiv);
      if (__any(m)) {
        uint32_t y0, y1;
        threefry2x32(kp0, kp1, rowbase + (uint32_t)j,
                     rowbase + (uint32_t)j + HALFC, y0, y1);
        uint32_t bits = (take_hi ? y1 : y0) >> 9;
        if (m && (bestj < 0 || bits > bestbits)) { bestbits = bits; bestj = j; }
      }
    }
    // wave-level lexicographic reduce: max bits, ties -> min j
    #pragma unroll
    for (int off = 32; off; off >>= 1) {
      uint32_t ob = (uint32_t)__shfl_xor((int)bestbits, off);
      int oj = __shfl_xor(bestj, off);
      if (oj >= 0 && (bestj < 0 || ob > bestbits ||
                      (ob == bestbits && oj < bestj))) {
        bestbits = ob; bestj = oj;
      }
    }
    int idx = (bestj >= 0) ? bestj : hard_idx[i];
    float neg_d = drow[idx];
    float tl = pos_d - neg_d + 1.0f;
    if (tl > 0.f) { wsum += (double)tl; wcnt++; }
  }

  if (lane == 0) { lsum[wave] = wsum; lcnt[wave] = wcnt; }
  __syncthreads();
  if (t == 0) {
    partials[bid] = lsum[0] + lsum[1] + lsum[2] + lsum[3];
    pcnt[bid] = (int)(lcnt[0] + lcnt[1] + lcnt[2] + lcnt[3]);
  }
}

// K3: deterministic fixed-order reduction of the 4096 block partials.
__global__ __launch_bounds__(256) void finalize_kernel(
    const double* __restrict__ partials, const int* __restrict__ pcnt,
    float* __restrict__ out) {
  __shared__ double ss[256];
  __shared__ int sc[256];
  int t = threadIdx.x;
  double s = 0.0;
  int c = 0;
  for (int k = t; k < NPART; k += 256) { s += partials[k]; c += pcnt[k]; }
  ss[t] = s; sc[t] = c;
  __syncthreads();
  for (int st = 128; st; st >>= 1) {
    if (t < st) { ss[t] += ss[t + st]; sc[t] += sc[t + st]; }
    __syncthreads();
  }
  if (t == 0) out[0] = sc[0] ? (float)(ss[0] / (double)sc[0]) : 0.0f;
}

extern "C" void kernel_launch(void* const* d_in, const int* in_sizes, int n_in,
                              void* d_out, int out_size, void* d_ws, size_t ws_size,
                              hipStream_t stream) {
  const float* emb = (const float*)d_in[0];
  const int* labels = (const int*)d_in[1];
  float* out = (float*)d_out;
  char* ws = (char*)d_ws;

  float* dist = (float*)ws;                         // 1 MB
  float* sq = (float*)(ws + 1048576);               // 2 KB
  int* hard_idx = (int*)(ws + 1048576 + 2048);      // 2 KB
  int* lists = (int*)(ws + 1048576 + 4096);         // 16 KB
  int* lcount = (int*)(ws + 1048576 + 4096 + 16384);        // 32 B (pad 2 KB)
  double* partials = (double*)(ws + 1048576 + 4096 + 18432); // 32 KB
  int* pcnt = (int*)(ws + 1048576 + 4096 + 18432 + 32768);   // 16 KB

  sq_kernel<<<B, 64, 0, stream>>>(emb, sq);
  list_kernel<<<1, 512, 0, stream>>>(labels, lists, lcount);
  dist_kernel<<<B, 256, 0, stream>>>(emb, sq, labels, dist, hard_idx);
  triplet_kernel<<<B * SPLIT, 256, 0, stream>>>(dist, labels, hard_idx, lists,
                                                lcount, partials, pcnt);
  finalize_kernel<<<1, 256, 0, stream>>>(partials, pcnt, out);
}

// Round 3
// 61.596 us; speedup vs baseline: 2.4494x; 1.4320x over previous
//
#include <hip/hip_runtime.h>
#include <stdint.h>

#define B 512
#define D 128
#define HALFC 131072u
#define SPLIT 8
#define NSLOT (SPLIT * 4)
#define NPART (B * SPLIT)

__device__ __forceinline__ uint32_t rotl32(uint32_t x, uint32_t r) {
  return (x << r) | (x >> (32u - r));
}

// Exact JAX/XLA threefry2x32 (20 rounds, key-schedule injections every 4).
__device__ __forceinline__ void threefry2x32(uint32_t k0, uint32_t k1,
                                             uint32_t x0, uint32_t x1,
                                             uint32_t& y0, uint32_t& y1) {
  uint32_t k2 = k0 ^ k1 ^ 0x1BD11BDAu;
  x0 += k0; x1 += k1;
#define TF_R(r) { x0 += x1; x1 = rotl32(x1, r); x1 ^= x0; }
  TF_R(13) TF_R(15) TF_R(26) TF_R(6)
  x0 += k1; x1 += k2 + 1u;
  TF_R(17) TF_R(29) TF_R(16) TF_R(24)
  x0 += k2; x1 += k0 + 2u;
  TF_R(13) TF_R(15) TF_R(26) TF_R(6)
  x0 += k0; x1 += k1 + 3u;
  TF_R(17) TF_R(29) TF_R(16) TF_R(24)
  x0 += k1; x1 += k2 + 4u;
  TF_R(13) TF_R(15) TF_R(26) TF_R(6)
  x0 += k2; x1 += k0 + 5u;
#undef TF_R
  y0 = x0; y1 = x1;
}

// K1: dist row i (sq fused: sq_j computed alongside dot, sq_i published via
// LDS by the thread whose column equals i) + hard-negative argmin.
__global__ __launch_bounds__(256) void dist_kernel(
    const float* __restrict__ emb, const int* __restrict__ labels,
    float* __restrict__ dist, int* __restrict__ hard_idx) {
  __shared__ float ei[D];
  __shared__ float sqi_sh;
  __shared__ float rmin[256];
  __shared__ int ridx[256];
  int i = blockIdx.x;
  int t = threadIdx.x;
  if (t < D) ei[t] = emb[(size_t)i * D + t];
  __syncthreads();
  const float4* e4i = reinterpret_cast<const float4*>(ei);
  float dot[2], sj[2];
  #pragma unroll
  for (int jj = 0; jj < 2; ++jj) {
    int j = t + jj * 256;
    const float4* ej = reinterpret_cast<const float4*>(emb + (size_t)j * D);
    float dacc = 0.f, sacc = 0.f;
    #pragma unroll
    for (int d4 = 0; d4 < D / 4; ++d4) {
      float4 v = ej[d4];
      float4 w = e4i[d4];
      dacc += v.x * w.x + v.y * w.y + v.z * w.z + v.w * w.w;
      sacc += v.x * v.x + v.y * v.y + v.z * v.z + v.w * v.w;
    }
    dot[jj] = dacc; sj[jj] = sacc;
    if (j == i) sqi_sh = sacc;
  }
  __syncthreads();
  float sqi = sqi_sh;
  int lab_i = labels[i];
  float bestv = 3.4e38f;
  int bestj = -1;
  #pragma unroll
  for (int jj = 0; jj < 2; ++jj) {
    int j = t + jj * 256;
    float d2 = sqi + sj[jj] - 2.f * dot[jj];
    float dd = sqrtf(fmaxf(d2, 0.f));
    dist[(size_t)i * B + j] = dd;
    if (labels[j] != lab_i) {
      if (bestj < 0 || dd < bestv) { bestv = dd; bestj = j; } // j asc -> first min
    }
  }
  rmin[t] = bestv; ridx[t] = bestj;
  __syncthreads();
  for (int s = 128; s; s >>= 1) {
    if (t < s) {
      float ov = rmin[t + s]; int oj = ridx[t + s];
      if (oj >= 0 && (ridx[t] < 0 || ov < rmin[t] ||
                      (ov == rmin[t] && oj < ridx[t]))) {
        rmin[t] = ov; ridx[t] = oj;
      }
    }
    __syncthreads();
  }
  if (t == 0) hard_idx[i] = (ridx[0] < 0) ? 0 : ridx[0];
}

// K2: SPLIT blocks per anchor p; in-block same-label list; per-row candidate
// compaction so threefry runs only on qualifying j's.
__global__ __launch_bounds__(256) void triplet_kernel(
    const float* __restrict__ dist, const int* __restrict__ labels,
    const int* __restrict__ hard_idx, double* __restrict__ partials,
    int* __restrict__ pcnt) {
  __shared__ unsigned short slab[B];
  __shared__ unsigned short list_sh[B];
  __shared__ unsigned short cand[4][B];
  __shared__ int nlist_sh;
  __shared__ double lsum[4];
  __shared__ unsigned int lcnt[4];
  int bid = blockIdx.x;
  int p = bid >> 3;  // SPLIT = 8
  int sub = bid & 7;
  int t = threadIdx.x;
  slab[t] = (unsigned short)labels[t];
  slab[t + 256] = (unsigned short)labels[t + 256];
  __syncthreads();
  int wave = t >> 6, lane = t & 63;
  int slot = sub * 4 + wave;
  unsigned long long lmask_lt = (1ull << lane) - 1ull;
  unsigned short lab_p = slab[p];

  // wave 0 builds the ascending list of rows with label lab_p
  if (wave == 0) {
    int n = 0;
    #pragma unroll
    for (int c = 0; c < 8; ++c) {
      int r = c * 64 + lane;
      bool v = (slab[r] == lab_p);
      unsigned long long mk = __ballot(v);
      if (v) list_sh[n + __popcll(mk & lmask_lt)] = (unsigned short)r;
      n += __popcll(mk);
    }
    if (lane == 0) nlist_sh = (n == B) ? 0 : n;  // n==B -> no negatives exist
  }

  // keys[p] from split(key(42), 512): out[i] = i<512 ? y0(i,i+512) : y1(i-512,i)
  uint32_t kp0, kp1;
  {
    uint32_t i0 = 2u * (uint32_t)p, i1 = i0 + 1u;
    uint32_t a0, a1, b0, b1;
    if (p < 256) {
      threefry2x32(0u, 42u, i0, i0 + 512u, a0, a1);
      threefry2x32(0u, 42u, i1, i1 + 512u, b0, b1);
      kp0 = a0; kp1 = b0;
    } else {
      threefry2x32(0u, 42u, i0 - 512u, i0, a0, a1);
      threefry2x32(0u, 42u, i1 - 512u, i1, b0, b1);
      kp0 = a1; kp1 = b1;
    }
  }
  __syncthreads();
  int nlist = nlist_sh;
  unsigned short* wcand = cand[wave];
  double wsum = 0.0;
  unsigned int wcnt = 0;

  for (int k = slot; k < nlist; k += NSLOT) {
    int i = list_sh[k];
    if (i == p) continue;
    const float* __restrict__ drow = dist + (size_t)i * B;
    float pos_d = drow[p];
    float hiv = pos_d + 1.0f;  // margin = 1.0
    uint32_t rowbase = (uint32_t)(((i < 256) ? i : (i - 256)) * B);
    bool take_hi = (i >= 256);

    float dd[8];
    #pragma unroll
    for (int jc = 0; jc < 8; ++jc) dd[jc] = drow[jc * 64 + lane];

    int nc = 0;
    #pragma unroll
    for (int jc = 0; jc < 8; ++jc) {
      int j = jc * 64 + lane;
      bool m = (slab[j] != lab_p) && (dd[jc] > pos_d) && (dd[jc] < hiv);
      unsigned long long mk = __ballot(m);
      if (m) wcand[nc + __popcll(mk & lmask_lt)] = (unsigned short)j;
      nc += __popcll(mk);
    }

    uint32_t bestbits = 0u;
    int bestj = -1;
    for (int c = lane; c < nc; c += 64) {
      int j = wcand[c];
      uint32_t y0, y1;
      threefry2x32(kp0, kp1, rowbase + (uint32_t)j,
                   rowbase + (uint32_t)j + HALFC, y0, y1);
      uint32_t bits = (take_hi ? y1 : y0) >> 9;
      // within-lane j ascends across iterations: strict > keeps lowest j
      if (bestj < 0 || bits > bestbits) { bestbits = bits; bestj = j; }
    }
    // cross-lane lexicographic reduce: max bits, ties -> min j
    #pragma unroll
    for (int off = 32; off; off >>= 1) {
      uint32_t ob = (uint32_t)__shfl_xor((int)bestbits, off);
      int oj = __shfl_xor(bestj, off);
      if (oj >= 0 && (bestj < 0 || ob > bestbits ||
                      (ob == bestbits && oj < bestj))) {
        bestbits = ob; bestj = oj;
      }
    }
    int idx = (bestj >= 0) ? bestj : hard_idx[i];
    float neg_d = drow[idx];
    float tl = pos_d - neg_d + 1.0f;
    if (tl > 0.f) { wsum += (double)tl; wcnt++; }
  }

  if (lane == 0) { lsum[wave] = wsum; lcnt[wave] = wcnt; }
  __syncthreads();
  if (t == 0) {
    partials[bid] = lsum[0] + lsum[1] + lsum[2] + lsum[3];
    pcnt[bid] = (int)(lcnt[0] + lcnt[1] + lcnt[2] + lcnt[3]);
  }
}

// K3: deterministic fixed-order reduction of the 4096 block partials.
__global__ __launch_bounds__(256) void finalize_kernel(
    const double* __restrict__ partials, const int* __restrict__ pcnt,
    float* __restrict__ out) {
  __shared__ double ss[256];
  __shared__ int sc[256];
  int t = threadIdx.x;
  double s = 0.0;
  int c = 0;
  for (int k = t; k < NPART; k += 256) { s += partials[k]; c += pcnt[k]; }
  ss[t] = s; sc[t] = c;
  __syncthreads();
  for (int st = 128; st; st >>= 1) {
    if (t < st) { ss[t] += ss[t + st]; sc[t] += sc[t + st]; }
    __syncthreads();
  }
  if (t == 0) out[0] = sc[0] ? (float)(ss[0] / (double)sc[0]) : 0.0f;
}

extern "C" void kernel_launch(void* const* d_in, const int* in_sizes, int n_in,
                              void* d_out, int out_size, void* d_ws, size_t ws_size,
                              hipStream_t stream) {
  const float* emb = (const float*)d_in[0];
  const int* labels = (const int*)d_in[1];
  float* out = (float*)d_out;
  char* ws = (char*)d_ws;

  float* dist = (float*)ws;                           // 1 MB
  int* hard_idx = (int*)(ws + 1048576);               // 2 KB
  double* partials = (double*)(ws + 1048576 + 2048);  // 32 KB
  int* pcnt = (int*)(ws + 1048576 + 2048 + 32768);    // 16 KB

  dist_kernel<<<B, 256, 0, stream>>>(emb, labels, dist, hard_idx);
  triplet_kernel<<<B * SPLIT, 256, 0, stream>>>(dist, labels, hard_idx,
                                                partials, pcnt);
  finalize_kernel<<<1, 256, 0, stream>>>(partials, pcnt, out);
}